// Round 7
// baseline (164.620 us; speedup 1.0000x reference)
//
#include <hip/hip_runtime.h>
#include <math.h>

#define HDIM   768
#define NSAMP  512
#define NLOG   513            // 1 target + 512 noise
#define VOCAB  50257
#define PADV   53248          // 1024 * 52, padded bin count for uint4 scan

// ---------------------------------------------------------------------------
// Sorted run-gather pipeline, 16-lane-group edition:
//  A) memsetAsync counts = 0
//  B) pre_kernel: fused {h -> PERMUTED packed bf16} + {vocab histogram}
//  C) single-block exclusive scan over padded bins (uint4 in/out) -> cursor
//  D) scatter: counting sort, payload only (tok<<10 | slot)
//  E) gather-run: ONE WAVE PER VOCAB RUN, FOUR OCCURRENCES PER ITERATION.
//     Wave = 4 groups x 16 lanes; each group owns one occurrence; all groups
//     share W[v] (12 float4/lane, registers, loaded once per run). h rows are
//     stored permuted so each group's 16 lanes read contiguous 256B chunks
//     (minimal cache-line touches). Reduce = 4 shfl_xor steps for 4 dots.
//     1-iteration-ahead software prefetch of payloads + h chunks.
//  F) per-token log-softmax + smoothed loss
//  G) deterministic mean
//
// Permuted bf16 row layout (u32 units, 384/row): t = 64*k + 4*p + j holds
// original u32 m = 24*p + 4*k + j (elems 2m,2m+1), p=lane&15, k=chunk 0..5.
// Lane p's W slice: elems [48p, 48p+48) = float4 wr[12p..12p+12).
// ---------------------------------------------------------------------------

// pack f32 -> bf16 (round-to-nearest-even)
__device__ __forceinline__ unsigned int bf16rn(float x)
{
    unsigned int u = __float_as_uint(x);
    return (u + 0x7fffu + ((u >> 16) & 1u)) >> 16;
}
__device__ __forceinline__ float blo(unsigned int u) { return __uint_as_float(u << 16); }
__device__ __forceinline__ float bhi(unsigned int u) { return __uint_as_float(u & 0xffff0000u); }

#define CONVB 128          // blocks doing h conversion
#define HISTB 384          // blocks doing histogram
__global__ __launch_bounds__(256) void pre_kernel(
    const float* __restrict__ h, unsigned int* __restrict__ hb,
    const int* __restrict__ target, const int* __restrict__ noise,
    unsigned int* __restrict__ counts, int N, int nhu)
{
    if (blockIdx.x < CONVB) {
        // permuted bf16 conversion
        int i = blockIdx.x * 256 + threadIdx.x;
        const int stride = CONVB * 256;
        for (; i < nhu; i += stride) {
            const int row = i / 384;
            const int q   = i - row * 384;
            const int k = q >> 6, r = q & 63;
            const int p = r >> 2, jj = r & 3;
            const int m = 24 * p + 4 * k + jj;
            const float2 pr = reinterpret_cast<const float2*>(h)[(size_t)row * 384 + m];
            hb[i] = bf16rn(pr.x) | (bf16rn(pr.y) << 16);
        }
    } else {
        int i = (blockIdx.x - CONVB) * 256 + threadIdx.x;
        const int stride = HISTB * 256;
        const int nn4 = (N * NSAMP) / 4;
        const int4* noise4 = reinterpret_cast<const int4*>(noise);
        for (int kk = i; kk < nn4; kk += stride) {
            const int4 vv = noise4[kk];
            atomicAdd(&counts[vv.x], 1u);
            atomicAdd(&counts[vv.y], 1u);
            atomicAdd(&counts[vv.z], 1u);
            atomicAdd(&counts[vv.w], 1u);
        }
        for (int kk = i; kk < N; kk += stride) atomicAdd(&counts[target[kk]], 1u);
    }
}

// single block, 1024 threads, 52 bins/thread, uint4 I/O (counts padded+zeroed)
__global__ __launch_bounds__(1024) void scan_kernel(
    const unsigned int* __restrict__ counts, unsigned int* __restrict__ cursor)
{
    const int tid = threadIdx.x;
    const uint4* c4 = reinterpret_cast<const uint4*>(counts) + tid * 13;
    uint4*      o4 = reinterpret_cast<uint4*>(cursor) + tid * 13;

    __shared__ unsigned int lds[1024];
    unsigned int s = 0;
    #pragma unroll
    for (int i = 0; i < 13; ++i) {
        const uint4 c = c4[i];
        s += c.x + c.y + c.z + c.w;
    }
    lds[tid] = s;
    __syncthreads();
    #pragma unroll
    for (int off = 1; off < 1024; off <<= 1) {
        unsigned int t = (tid >= off) ? lds[tid - off] : 0u;
        __syncthreads();
        lds[tid] += t;
        __syncthreads();
    }
    unsigned int run = (tid > 0) ? lds[tid - 1] : 0u;   // exclusive prefix
    #pragma unroll
    for (int i = 0; i < 13; ++i) {
        const uint4 c = c4[i];
        uint4 o;
        o.x = run;
        o.y = o.x + c.x;
        o.z = o.y + c.y;
        o.w = o.z + c.z;
        run = o.w + c.w;
        o4[i] = o;
    }
}

__global__ __launch_bounds__(256) void scatter_kernel(
    const int* __restrict__ target, const int* __restrict__ noise,
    unsigned int* __restrict__ cursor,
    unsigned int* __restrict__ sorted_pay, int N)
{
    int i = blockIdx.x * 256 + threadIdx.x;
    int stride = gridDim.x * 256;
    const int nn4 = (N * NSAMP) / 4;
    const int4* noise4 = reinterpret_cast<const int4*>(noise);
    for (int k = i; k < nn4; k += stride) {
        const int4 vv = noise4[k];
        const int kk = k * 4;
        #pragma unroll
        for (int j = 0; j < 4; ++j) {
            const int v    = (j == 0) ? vv.x : (j == 1) ? vv.y : (j == 2) ? vv.z : vv.w;
            const int idx  = kk + j;
            const int tok  = idx >> 9;            // /512
            const int slot = (idx & 511) + 1;     // noise -> slots 1..512
            const unsigned int pos = atomicAdd(&cursor[v], 1u);
            sorted_pay[pos] = ((unsigned int)tok << 10) | (unsigned int)slot;
        }
    }
    for (int k = i; k < N; k += stride) {
        const int v = target[k];
        const unsigned int pos = atomicAdd(&cursor[v], 1u);
        sorted_pay[pos] = ((unsigned int)k << 10);   // slot 0
    }
}

// 8 products of one permuted-bf16 uint4 against two W float4s
#define DOT8(X, WA, WB) \
    (blo(X.x)*WA.x + bhi(X.x)*WA.y + blo(X.y)*WA.z + bhi(X.y)*WA.w + \
     blo(X.z)*WB.x + bhi(X.z)*WB.y + blo(X.w)*WB.z + bhi(X.w)*WB.w)

// one wave per vocab run; wave = 4 groups x 16 lanes; 4 occurrences/iteration
#define GTPB 256
__global__ __launch_bounds__(GTPB) void gather_run_kernel(
    const unsigned int* __restrict__ hb,          // permuted bf16 h, 384 u32/row
    const float* __restrict__ W,
    const unsigned int* __restrict__ counts,
    const unsigned int* __restrict__ cursor,      // end offsets after scatter
    const unsigned int* __restrict__ sorted_pay,
    float* __restrict__ logits)
{
    const int v = blockIdx.x * (GTPB / 64) + (threadIdx.x >> 6);
    if (v >= VOCAB) return;
    const int cnt = (int)counts[v];
    if (cnt == 0) return;
    const int start = (int)cursor[v] - cnt;
    const int lane  = threadIdx.x & 63;
    const int p     = lane & 15;                  // position in group
    const int g     = lane >> 4;                  // group id 0..3
    const int last  = cnt - 1;

    // W fragment (fp32, registers for the whole run): elems [48p, 48p+48)
    const float4* wr = reinterpret_cast<const float4*>(W + (size_t)v * HDIM);
    float4 wf[12];
    #pragma unroll
    for (int k = 0; k < 12; ++k) wf[k] = wr[12 * p + k];

    const unsigned int* sp = sorted_pay + start;

    // prologue: group g's first occurrence (clamped)
    int idx0 = (g < last) ? g : last;
    unsigned int pay = sp[idx0];
    const uint4* hr = reinterpret_cast<const uint4*>(hb) + (size_t)(pay >> 10) * 96;
    uint4 x0 = hr[p],      x1 = hr[p + 16], x2 = hr[p + 32],
          x3 = hr[p + 48], x4 = hr[p + 64], x5 = hr[p + 80];

    for (int j = 0; j < cnt; j += 4) {
        // prefetch next iteration's occurrence for this group (clamped)
        const int jn  = j + 4 + g;
        const int idn = (jn < last) ? jn : last;
        const unsigned int payn = sp[idn];
        const uint4* hn = reinterpret_cast<const uint4*>(hb) + (size_t)(payn >> 10) * 96;
        const uint4 n0 = hn[p],      n1 = hn[p + 16], n2 = hn[p + 32],
                    n3 = hn[p + 48], n4 = hn[p + 64], n5 = hn[p + 80];

        float s;
        s  = DOT8(x0, wf[0],  wf[1]);
        s += DOT8(x1, wf[2],  wf[3]);
        s += DOT8(x2, wf[4],  wf[5]);
        s += DOT8(x3, wf[6],  wf[7]);
        s += DOT8(x4, wf[8],  wf[9]);
        s += DOT8(x5, wf[10], wf[11]);

        // 16-lane group reduce (4 steps, reduces all 4 occurrences at once)
        #pragma unroll
        for (int off = 8; off; off >>= 1) s += __shfl_xor(s, off, 64);

        if (p == 0 && j + g <= last)
            logits[(size_t)(pay >> 10) * NLOG + (pay & 1023u)] = s;

        pay = payn;
        x0 = n0; x1 = n1; x2 = n2; x3 = n3; x4 = n4; x5 = n5;
    }
}

__global__ __launch_bounds__(256) void softmax_loss_kernel(
    const float* __restrict__ logits, float* __restrict__ loss_per_token)
{
    const int n    = blockIdx.x;
    const int tid  = threadIdx.x;
    const int lane = tid & 63;
    const int wave = tid >> 6;
    const float* row = logits + (size_t)n * NLOG;

    __shared__ float red[4];
    __shared__ float red2[4][2];

    float lmax = -INFINITY;
    for (int r = tid; r < NLOG; r += 256) lmax = fmaxf(lmax, row[r]);
    #pragma unroll
    for (int off = 32; off; off >>= 1) lmax = fmaxf(lmax, __shfl_xor(lmax, off, 64));
    if (lane == 0) red[wave] = lmax;
    __syncthreads();
    lmax = fmaxf(fmaxf(red[0], red[1]), fmaxf(red[2], red[3]));

    float esum = 0.f, lsum = 0.f;
    for (int r = tid; r < NLOG; r += 256) {
        const float l = row[r];
        esum += __expf(l - lmax);
        if (r > 0) lsum += l;
    }
    #pragma unroll
    for (int off = 32; off; off >>= 1) {
        esum += __shfl_xor(esum, off, 64);
        lsum += __shfl_xor(lsum, off, 64);
    }
    if (lane == 0) { red2[wave][0] = esum; red2[wave][1] = lsum; }
    __syncthreads();

    if (tid == 0) {
        esum = red2[0][0] + red2[1][0] + red2[2][0] + red2[3][0];
        lsum = red2[0][1] + red2[1][1] + red2[2][1] + red2[3][1];
        const float lse  = lmax + logf(esum);
        const float l0   = row[0];
        const float loss = -0.9f * (l0 - lse)
                         - (0.1f / 512.f) * (lsum - 512.f * lse);
        loss_per_token[n] = loss;
    }
}

__global__ __launch_bounds__(256) void reduce_mean_kernel(
    const float* __restrict__ x, float* __restrict__ out, int n)
{
    const int tid = threadIdx.x;
    float s = 0.f;
    for (int i = tid; i < n; i += 256) s += x[i];
    #pragma unroll
    for (int off = 32; off; off >>= 1) s += __shfl_xor(s, off, 64);
    __shared__ float red[4];
    if ((tid & 63) == 0) red[tid >> 6] = s;
    __syncthreads();
    if (tid == 0) out[0] = (red[0] + red[1] + red[2] + red[3]) / (float)n;
}

// ------------------------- legacy fallback (R1) ----------------------------
__global__ __launch_bounds__(512) void nce_token_kernel(
    const float* __restrict__ h, const float* __restrict__ W,
    const int* __restrict__ target, const int* __restrict__ noise,
    float* __restrict__ loss_per_token)
{
    const int n    = blockIdx.x;
    const int tid  = threadIdx.x;
    const int lane = tid & 63;
    const int wave = tid >> 6;

    __shared__ float  logits[NLOG];
    __shared__ float4 hsm[HDIM / 4];
    __shared__ float  red[8];
    __shared__ float  red2[8][2];

    const float4* hrow = reinterpret_cast<const float4*>(h + (size_t)n * HDIM);
    if (tid < HDIM / 4) hsm[tid] = hrow[tid];
    __syncthreads();

    const float4 h0 = hsm[lane];
    const float4 h1 = hsm[lane + 64];
    const float4 h2 = hsm[lane + 128];
    const int* nrow = noise + (size_t)n * NSAMP;

    for (int r = wave; r < NLOG; r += 8) {
        const int row = (r == 0) ? target[n] : nrow[r - 1];
        const float4* wr = reinterpret_cast<const float4*>(W + (size_t)row * HDIM);
        const float4 w0 = wr[lane];
        const float4 w1 = wr[lane + 64];
        const float4 w2 = wr[lane + 128];
        float s;
        s  = h0.x * w0.x + h0.y * w0.y + h0.z * w0.z + h0.w * w0.w;
        s += h1.x * w1.x + h1.y * w1.y + h1.z * w1.z + h1.w * w1.w;
        s += h2.x * w2.x + h2.y * w2.y + h2.z * w2.z + h2.w * w2.w;
        #pragma unroll
        for (int off = 32; off; off >>= 1) s += __shfl_xor(s, off, 64);
        if (lane == 0) logits[r] = s;
    }
    __syncthreads();

    float lmax = -INFINITY;
    for (int r = tid; r < NLOG; r += 512) lmax = fmaxf(lmax, logits[r]);
    #pragma unroll
    for (int off = 32; off; off >>= 1) lmax = fmaxf(lmax, __shfl_xor(lmax, off, 64));
    if (lane == 0) red[wave] = lmax;
    __syncthreads();
    if (wave == 0) {
        float m = (lane < 8) ? red[lane] : -INFINITY;
        #pragma unroll
        for (int off = 4; off; off >>= 1) m = fmaxf(m, __shfl_xor(m, off, 64));
        if (lane == 0) red[0] = m;
    }
    __syncthreads();
    lmax = red[0];

    float esum = 0.f, lsum = 0.f;
    for (int r = tid; r < NLOG; r += 512) {
        const float l = logits[r];
        esum += __expf(l - lmax);
        if (r > 0) lsum += l;
    }
    #pragma unroll
    for (int off = 32; off; off >>= 1) {
        esum += __shfl_xor(esum, off, 64);
        lsum += __shfl_xor(lsum, off, 64);
    }
    if (lane == 0) { red2[wave][0] = esum; red2[wave][1] = lsum; }
    __syncthreads();

    if (tid == 0) {
        esum = 0.f; lsum = 0.f;
        #pragma unroll
        for (int w = 0; w < 8; ++w) { esum += red2[w][0]; lsum += red2[w][1]; }
        const float lse  = lmax + logf(esum);
        const float loss = -0.9f * (logits[0] - lse)
                         - (0.1f / 512.f) * (lsum - 512.f * lse);
        loss_per_token[n] = loss;
    }
}
// ---------------------------------------------------------------------------

extern "C" void kernel_launch(void* const* d_in, const int* in_sizes, int n_in,
                              void* d_out, int out_size, void* d_ws, size_t ws_size,
                              hipStream_t stream)
{
    const float* h      = (const float*)d_in[0];   // [N, 768] fp32
    const float* W      = (const float*)d_in[1];   // [50257, 768] fp32
    const int*   target = (const int*)d_in[2];     // [N] int32
    const int*   noise  = (const int*)d_in[3];     // [N, 512] int32
    float*       out    = (float*)d_out;
    const int    N      = in_sizes[2];             // 1024 tokens
    const int    nocc   = N * NLOG;                // 525312
    const int    nh2    = N * HDIM / 2;            // 393216 packed u32

    // ws layout (u32/f32 elements): counts[PADV] cursor[PADV] pay[nocc]
    //                               hb[nh2] logits[nocc] loss[N]
    unsigned int* counts     = (unsigned int*)d_ws;
    unsigned int* cursor     = counts + PADV;
    unsigned int* sorted_pay = cursor + PADV;
    unsigned int* hb         = sorted_pay + nocc;
    float*        logits     = (float*)(hb + nh2);
    float*        loss       = logits + nocc;
    const size_t  need_bytes = (size_t)(2 * PADV + 2 * nocc + nh2 + N) * 4;

    if (ws_size < need_bytes) {
        // fallback: direct gather path (R1)
        float* ws = (float*)d_ws;
        nce_token_kernel<<<N, 512, 0, stream>>>(h, W, target, noise, ws);
        reduce_mean_kernel<<<1, 256, 0, stream>>>(ws, out, N);
        return;
    }

    hipMemsetAsync(counts, 0, (size_t)PADV * 4, stream);
    pre_kernel<<<CONVB + HISTB, 256, 0, stream>>>(h, hb, target, noise,
                                                  counts, N, nh2);
    scan_kernel<<<1, 1024, 0, stream>>>(counts, cursor);
    scatter_kernel<<<512, 256, 0, stream>>>(target, noise, cursor, sorted_pay, N);
    const int gblocks = (VOCAB + (GTPB / 64) - 1) / (GTPB / 64);
    gather_run_kernel<<<gblocks, GTPB, 0, stream>>>(hb, W, counts, cursor,
                                                    sorted_pay, logits);
    softmax_loss_kernel<<<N, 256, 0, stream>>>(logits, loss);
    reduce_mean_kernel<<<1, 256, 0, stream>>>(loss, out, N);
}

// Round 8
// 153.369 us; speedup vs baseline: 1.0734x; 1.0734x over previous
//
#include <hip/hip_runtime.h>
#include <hip/hip_fp16.h>
#include <math.h>

#define HDIM   768
#define NSAMP  512
#define NLOG   513            // 1 target + 512 noise
#define VOCAB  50257
#define PADV   53248          // 1024 * 52, padded bin count for uint4 scan

// ---------------------------------------------------------------------------
// Sorted run-gather pipeline, fp16-dot2 edition (R6 skeleton + v_dot2):
//  A) memsetAsync counts = 0
//  B) pre_kernel: fused {h -> packed fp16 (linear layout)} + {vocab histogram}
//  C) single-block exclusive scan over padded bins (uint4 in/out) -> cursor
//  D) scatter: counting sort, payload only (tok<<10 | slot)
//  E) gather-run: ONE WAVE PER VOCAB RUN, 2 occurrences/iteration, 3-stage
//     software pipeline (prefetch 2 iterations ahead). W lane-slice converted
//     to packed fp16 once per run; each occurrence = 6 x v_dot2_f32_f16
//     (fp16 pair-dot, f32 accumulate) instead of 12 unpack + 12 FMA.
//  F) per-token log-softmax + smoothed loss
//  G) deterministic mean
// ---------------------------------------------------------------------------

typedef _Float16 h2_t __attribute__((ext_vector_type(2)));

__device__ __forceinline__ unsigned int pkh(float x, float y)
{
    const unsigned lo = __half_as_ushort(__float2half_rn(x));
    const unsigned hi = __half_as_ushort(__float2half_rn(y));
    return lo | (hi << 16);
}

__device__ __forceinline__ float dot2(unsigned int a, unsigned int b, float c)
{
#if __has_builtin(__builtin_amdgcn_fdot2)
    return __builtin_amdgcn_fdot2(__builtin_bit_cast(h2_t, a),
                                  __builtin_bit_cast(h2_t, b), c, false);
#else
    const h2_t ha = __builtin_bit_cast(h2_t, a);
    const h2_t hb = __builtin_bit_cast(h2_t, b);
    return c + (float)ha.x * (float)hb.x + (float)ha.y * (float)hb.y;
#endif
}

#define CONVB 128          // blocks doing h conversion
#define HISTB 384          // blocks doing histogram
__global__ __launch_bounds__(256) void pre_kernel(
    const float* __restrict__ h, unsigned int* __restrict__ hb,
    const int* __restrict__ target, const int* __restrict__ noise,
    unsigned int* __restrict__ counts, int N, int nhu)
{
    if (blockIdx.x < CONVB) {
        // linear packed-fp16 conversion: hb[i] = fp16(h[2i]) | fp16(h[2i+1])<<16
        int i = blockIdx.x * 256 + threadIdx.x;
        const int stride = CONVB * 256;
        for (; i < nhu; i += stride) {
            const float2 pr = reinterpret_cast<const float2*>(h)[i];
            hb[i] = pkh(pr.x, pr.y);
        }
    } else {
        int i = (blockIdx.x - CONVB) * 256 + threadIdx.x;
        const int stride = HISTB * 256;
        const int nn4 = (N * NSAMP) / 4;
        const int4* noise4 = reinterpret_cast<const int4*>(noise);
        for (int kk = i; kk < nn4; kk += stride) {
            const int4 vv = noise4[kk];
            atomicAdd(&counts[vv.x], 1u);
            atomicAdd(&counts[vv.y], 1u);
            atomicAdd(&counts[vv.z], 1u);
            atomicAdd(&counts[vv.w], 1u);
        }
        for (int kk = i; kk < N; kk += stride) atomicAdd(&counts[target[kk]], 1u);
    }
}

// single block, 1024 threads, 52 bins/thread, uint4 I/O (counts padded+zeroed)
__global__ __launch_bounds__(1024) void scan_kernel(
    const unsigned int* __restrict__ counts, unsigned int* __restrict__ cursor)
{
    const int tid = threadIdx.x;
    const uint4* c4 = reinterpret_cast<const uint4*>(counts) + tid * 13;
    uint4*      o4 = reinterpret_cast<uint4*>(cursor) + tid * 13;

    __shared__ unsigned int lds[1024];
    unsigned int s = 0;
    #pragma unroll
    for (int i = 0; i < 13; ++i) {
        const uint4 c = c4[i];
        s += c.x + c.y + c.z + c.w;
    }
    lds[tid] = s;
    __syncthreads();
    #pragma unroll
    for (int off = 1; off < 1024; off <<= 1) {
        unsigned int t = (tid >= off) ? lds[tid - off] : 0u;
        __syncthreads();
        lds[tid] += t;
        __syncthreads();
    }
    unsigned int run = (tid > 0) ? lds[tid - 1] : 0u;   // exclusive prefix
    #pragma unroll
    for (int i = 0; i < 13; ++i) {
        const uint4 c = c4[i];
        uint4 o;
        o.x = run;
        o.y = o.x + c.x;
        o.z = o.y + c.y;
        o.w = o.z + c.z;
        run = o.w + c.w;
        o4[i] = o;
    }
}

__global__ __launch_bounds__(256) void scatter_kernel(
    const int* __restrict__ target, const int* __restrict__ noise,
    unsigned int* __restrict__ cursor,
    unsigned int* __restrict__ sorted_pay, int N)
{
    int i = blockIdx.x * 256 + threadIdx.x;
    int stride = gridDim.x * 256;
    const int nn4 = (N * NSAMP) / 4;
    const int4* noise4 = reinterpret_cast<const int4*>(noise);
    for (int k = i; k < nn4; k += stride) {
        const int4 vv = noise4[k];
        const int kk = k * 4;
        #pragma unroll
        for (int j = 0; j < 4; ++j) {
            const int v    = (j == 0) ? vv.x : (j == 1) ? vv.y : (j == 2) ? vv.z : vv.w;
            const int idx  = kk + j;
            const int tok  = idx >> 9;            // /512
            const int slot = (idx & 511) + 1;     // noise -> slots 1..512
            const unsigned int pos = atomicAdd(&cursor[v], 1u);
            sorted_pay[pos] = ((unsigned int)tok << 10) | (unsigned int)slot;
        }
    }
    for (int k = i; k < N; k += stride) {
        const int v = target[k];
        const unsigned int pos = atomicAdd(&cursor[v], 1u);
        sorted_pay[pos] = ((unsigned int)k << 10);   // slot 0
    }
}

// one wave per vocab run; 2 occurrences/iter; 3-stage pipeline; fp16 dot2
#define GTPB 256
__global__ __launch_bounds__(GTPB) void gather_run_kernel(
    const unsigned int* __restrict__ hb,          // packed fp16 h, 384 u32/row
    const float* __restrict__ W,
    const unsigned int* __restrict__ counts,
    const unsigned int* __restrict__ cursor,      // end offsets after scatter
    const unsigned int* __restrict__ sorted_pay,
    float* __restrict__ logits)
{
    const int v = blockIdx.x * (GTPB / 64) + (threadIdx.x >> 6);
    if (v >= VOCAB) return;
    const int cnt = (int)counts[v];
    if (cnt == 0) return;
    const int start = (int)cursor[v] - cnt;
    const int lane  = threadIdx.x & 63;
    const int last  = cnt - 1;

    // W row lane-slice -> packed fp16, registers for the whole run.
    // Lane covers elems [8*lane, 8*lane+8) and [512+4*lane, 512+4*lane+4).
    const float4* wr = reinterpret_cast<const float4*>(W + (size_t)v * HDIM);
    const float4 a0 = wr[2 * lane], a1 = wr[2 * lane + 1], a2 = wr[128 + lane];
    const unsigned wp0 = pkh(a0.x, a0.y), wp1 = pkh(a0.z, a0.w),
                   wp2 = pkh(a1.x, a1.y), wp3 = pkh(a1.z, a1.w),
                   wp4 = pkh(a2.x, a2.y), wp5 = pkh(a2.z, a2.w);

    const unsigned int* sp = sorted_pay + start;
    #define CLMP(k) ((k) < last ? (k) : last)

    // prologue: stages 0 (pays 0,1) and 1 (pays 2,3)
    unsigned pay0 = sp[0];
    unsigned pay1 = sp[CLMP(1)];
    unsigned pay2 = sp[CLMP(2)];
    unsigned pay3 = sp[CLMP(3)];
    const unsigned* r0 = hb + (size_t)(pay0 >> 10) * 384;
    const unsigned* r1 = hb + (size_t)(pay1 >> 10) * 384;
    const unsigned* r2 = hb + (size_t)(pay2 >> 10) * 384;
    const unsigned* r3 = hb + (size_t)(pay3 >> 10) * 384;
    uint4 x0 = reinterpret_cast<const uint4*>(r0)[lane];
    uint2 y0 = reinterpret_cast<const uint2*>(r0 + 256)[lane];
    uint4 x1 = reinterpret_cast<const uint4*>(r1)[lane];
    uint2 y1 = reinterpret_cast<const uint2*>(r1 + 256)[lane];
    uint4 x2 = reinterpret_cast<const uint4*>(r2)[lane];
    uint2 y2 = reinterpret_cast<const uint2*>(r2 + 256)[lane];
    uint4 x3 = reinterpret_cast<const uint4*>(r3)[lane];
    uint2 y3 = reinterpret_cast<const uint2*>(r3 + 256)[lane];

    for (int j = 0; j < cnt; j += 2) {
        // prefetch stage j+4, j+5 (clamped)
        const unsigned payn0 = sp[CLMP(j + 4)];
        const unsigned payn1 = sp[CLMP(j + 5)];
        const unsigned* rn0 = hb + (size_t)(payn0 >> 10) * 384;
        const unsigned* rn1 = hb + (size_t)(payn1 >> 10) * 384;
        const uint4 nx0 = reinterpret_cast<const uint4*>(rn0)[lane];
        const uint2 ny0 = reinterpret_cast<const uint2*>(rn0 + 256)[lane];
        const uint4 nx1 = reinterpret_cast<const uint4*>(rn1)[lane];
        const uint2 ny1 = reinterpret_cast<const uint2*>(rn1 + 256)[lane];

        // two occurrences, 6 dot2 each, 2 chains per occurrence for ILP
        float s0a = dot2(x0.x, wp0, 0.f), s1a = dot2(x1.x, wp0, 0.f);
        float s0b = dot2(x0.y, wp1, 0.f), s1b = dot2(x1.y, wp1, 0.f);
        s0a = dot2(x0.z, wp2, s0a);  s1a = dot2(x1.z, wp2, s1a);
        s0b = dot2(x0.w, wp3, s0b);  s1b = dot2(x1.w, wp3, s1b);
        s0a = dot2(y0.x, wp4, s0a);  s1a = dot2(y1.x, wp4, s1a);
        s0b = dot2(y0.y, wp5, s0b);  s1b = dot2(y1.y, wp5, s1b);
        float s0 = s0a + s0b, s1 = s1a + s1b;

        // interleaved 64-lane reductions
        #pragma unroll
        for (int off = 32; off; off >>= 1) {
            s0 += __shfl_xor(s0, off, 64);
            s1 += __shfl_xor(s1, off, 64);
        }
        if (lane == 0) {
            logits[(size_t)(pay0 >> 10) * NLOG + (pay0 & 1023u)] = s0;
            if (j + 1 < cnt)
                logits[(size_t)(pay1 >> 10) * NLOG + (pay1 & 1023u)] = s1;
        }

        // rotate pipeline
        pay0 = pay2; pay1 = pay3; pay2 = payn0; pay3 = payn1;
        x0 = x2; y0 = y2; x1 = x3; y1 = y3;
        x2 = nx0; y2 = ny0; x3 = nx1; y3 = ny1;
    }
    #undef CLMP
}

__global__ __launch_bounds__(256) void softmax_loss_kernel(
    const float* __restrict__ logits, float* __restrict__ loss_per_token)
{
    const int n    = blockIdx.x;
    const int tid  = threadIdx.x;
    const int lane = tid & 63;
    const int wave = tid >> 6;
    const float* row = logits + (size_t)n * NLOG;

    __shared__ float red[4];
    __shared__ float red2[4][2];

    float lmax = -INFINITY;
    for (int r = tid; r < NLOG; r += 256) lmax = fmaxf(lmax, row[r]);
    #pragma unroll
    for (int off = 32; off; off >>= 1) lmax = fmaxf(lmax, __shfl_xor(lmax, off, 64));
    if (lane == 0) red[wave] = lmax;
    __syncthreads();
    lmax = fmaxf(fmaxf(red[0], red[1]), fmaxf(red[2], red[3]));

    float esum = 0.f, lsum = 0.f;
    for (int r = tid; r < NLOG; r += 256) {
        const float l = row[r];
        esum += __expf(l - lmax);
        if (r > 0) lsum += l;
    }
    #pragma unroll
    for (int off = 32; off; off >>= 1) {
        esum += __shfl_xor(esum, off, 64);
        lsum += __shfl_xor(lsum, off, 64);
    }
    if (lane == 0) { red2[wave][0] = esum; red2[wave][1] = lsum; }
    __syncthreads();

    if (tid == 0) {
        esum = red2[0][0] + red2[1][0] + red2[2][0] + red2[3][0];
        lsum = red2[0][1] + red2[1][1] + red2[2][1] + red2[3][1];
        const float lse  = lmax + logf(esum);
        const float l0   = row[0];
        const float loss = -0.9f * (l0 - lse)
                         - (0.1f / 512.f) * (lsum - 512.f * lse);
        loss_per_token[n] = loss;
    }
}

__global__ __launch_bounds__(256) void reduce_mean_kernel(
    const float* __restrict__ x, float* __restrict__ out, int n)
{
    const int tid = threadIdx.x;
    float s = 0.f;
    for (int i = tid; i < n; i += 256) s += x[i];
    #pragma unroll
    for (int off = 32; off; off >>= 1) s += __shfl_xor(s, off, 64);
    __shared__ float red[4];
    if ((tid & 63) == 0) red[tid >> 6] = s;
    __syncthreads();
    if (tid == 0) out[0] = (red[0] + red[1] + red[2] + red[3]) / (float)n;
}

// ------------------------- legacy fallback (R1) ----------------------------
__global__ __launch_bounds__(512) void nce_token_kernel(
    const float* __restrict__ h, const float* __restrict__ W,
    const int* __restrict__ target, const int* __restrict__ noise,
    float* __restrict__ loss_per_token)
{
    const int n    = blockIdx.x;
    const int tid  = threadIdx.x;
    const int lane = tid & 63;
    const int wave = tid >> 6;

    __shared__ float  logits[NLOG];
    __shared__ float4 hsm[HDIM / 4];
    __shared__ float  red[8];
    __shared__ float  red2[8][2];

    const float4* hrow = reinterpret_cast<const float4*>(h + (size_t)n * HDIM);
    if (tid < HDIM / 4) hsm[tid] = hrow[tid];
    __syncthreads();

    const float4 h0 = hsm[lane];
    const float4 h1 = hsm[lane + 64];
    const float4 h2 = hsm[lane + 128];
    const int* nrow = noise + (size_t)n * NSAMP;

    for (int r = wave; r < NLOG; r += 8) {
        const int row = (r == 0) ? target[n] : nrow[r - 1];
        const float4* wr = reinterpret_cast<const float4*>(W + (size_t)row * HDIM);
        const float4 w0 = wr[lane];
        const float4 w1 = wr[lane + 64];
        const float4 w2 = wr[lane + 128];
        float s;
        s  = h0.x * w0.x + h0.y * w0.y + h0.z * w0.z + h0.w * w0.w;
        s += h1.x * w1.x + h1.y * w1.y + h1.z * w1.z + h1.w * w1.w;
        s += h2.x * w2.x + h2.y * w2.y + h2.z * w2.z + h2.w * w2.w;
        #pragma unroll
        for (int off = 32; off; off >>= 1) s += __shfl_xor(s, off, 64);
        if (lane == 0) logits[r] = s;
    }
    __syncthreads();

    float lmax = -INFINITY;
    for (int r = tid; r < NLOG; r += 512) lmax = fmaxf(lmax, logits[r]);
    #pragma unroll
    for (int off = 32; off; off >>= 1) lmax = fmaxf(lmax, __shfl_xor(lmax, off, 64));
    if (lane == 0) red[wave] = lmax;
    __syncthreads();
    if (wave == 0) {
        float m = (lane < 8) ? red[lane] : -INFINITY;
        #pragma unroll
        for (int off = 4; off; off >>= 1) m = fmaxf(m, __shfl_xor(m, off, 64));
        if (lane == 0) red[0] = m;
    }
    __syncthreads();
    lmax = red[0];

    float esum = 0.f, lsum = 0.f;
    for (int r = tid; r < NLOG; r += 512) {
        const float l = logits[r];
        esum += __expf(l - lmax);
        if (r > 0) lsum += l;
    }
    #pragma unroll
    for (int off = 32; off; off >>= 1) {
        esum += __shfl_xor(esum, off, 64);
        lsum += __shfl_xor(lsum, off, 64);
    }
    if (lane == 0) { red2[wave][0] = esum; red2[wave][1] = lsum; }
    __syncthreads();

    if (tid == 0) {
        esum = 0.f; lsum = 0.f;
        #pragma unroll
        for (int w = 0; w < 8; ++w) { esum += red2[w][0]; lsum += red2[w][1]; }
        const float lse  = lmax + logf(esum);
        const float loss = -0.9f * (logits[0] - lse)
                         - (0.1f / 512.f) * (lsum - 512.f * lse);
        loss_per_token[n] = loss;
    }
}
// ---------------------------------------------------------------------------

extern "C" void kernel_launch(void* const* d_in, const int* in_sizes, int n_in,
                              void* d_out, int out_size, void* d_ws, size_t ws_size,
                              hipStream_t stream)
{
    const float* h      = (const float*)d_in[0];   // [N, 768] fp32
    const float* W      = (const float*)d_in[1];   // [50257, 768] fp32
    const int*   target = (const int*)d_in[2];     // [N] int32
    const int*   noise  = (const int*)d_in[3];     // [N, 512] int32
    float*       out    = (float*)d_out;
    const int    N      = in_sizes[2];             // 1024 tokens
    const int    nocc   = N * NLOG;                // 525312
    const int    nh2    = N * HDIM / 2;            // 393216 packed u32

    // ws layout (u32/f32 elements): counts[PADV] cursor[PADV] pay[nocc]
    //                               hb[nh2] logits[nocc] loss[N]
    unsigned int* counts     = (unsigned int*)d_ws;
    unsigned int* cursor     = counts + PADV;
    unsigned int* sorted_pay = cursor + PADV;
    unsigned int* hb         = sorted_pay + nocc;
    float*        logits     = (float*)(hb + nh2);
    float*        loss       = logits + nocc;
    const size_t  need_bytes = (size_t)(2 * PADV + 2 * nocc + nh2 + N) * 4;

    if (ws_size < need_bytes) {
        // fallback: direct gather path (R1)
        float* ws = (float*)d_ws;
        nce_token_kernel<<<N, 512, 0, stream>>>(h, W, target, noise, ws);
        reduce_mean_kernel<<<1, 256, 0, stream>>>(ws, out, N);
        return;
    }

    hipMemsetAsync(counts, 0, (size_t)PADV * 4, stream);
    pre_kernel<<<CONVB + HISTB, 256, 0, stream>>>(h, hb, target, noise,
                                                  counts, N, nh2);
    scan_kernel<<<1, 1024, 0, stream>>>(counts, cursor);
    scatter_kernel<<<512, 256, 0, stream>>>(target, noise, cursor, sorted_pay, N);
    const int gblocks = (VOCAB + (GTPB / 64) - 1) / (GTPB / 64);
    gather_run_kernel<<<gblocks, GTPB, 0, stream>>>(hb, W, counts, cursor,
                                                    sorted_pay, logits);
    softmax_loss_kernel<<<N, 256, 0, stream>>>(logits, loss);
    reduce_mean_kernel<<<1, 256, 0, stream>>>(loss, out, N);
}

// Round 9
// 152.758 us; speedup vs baseline: 1.0777x; 1.0040x over previous
//
#include <hip/hip_runtime.h>
#include <hip/hip_fp16.h>
#include <math.h>

#define HDIM   768
#define NSAMP  512
#define NLOG   513            // 1 target + 512 noise
#define VOCAB  50257
#define PADV   53248          // 1024 * 52, padded bin count for uint4 scan

// ---------------------------------------------------------------------------
// Sorted run-gather pipeline, fp16-dot2 + DPP-reduce edition:
//  A) memsetAsync counts = 0
//  B) pre_kernel: fused {h -> packed fp16 (linear layout)} + {vocab histogram}
//  C) single-block exclusive scan over padded bins (uint4 in/out) -> cursor
//  D) scatter: counting sort, payload only (tok<<10 | slot)
//  E) gather-run: ONE WAVE PER VOCAB RUN, 2 occurrences/iteration, 3-stage
//     software pipeline. W lane-slice packed fp16 once per run; 6 x v_dot2
//     per occurrence. Reduce: 4 DPP row_ror adds (VALU, intra-16) + 1
//     ds_swizzle xor16 per occurrence + ONE shared shfl_xor(32) for both
//     occurrences via select-combine -> 3 DS ops/iter instead of 12.
//  F) per-token log-softmax + smoothed loss
//  G) deterministic mean
// ---------------------------------------------------------------------------

typedef _Float16 h2_t __attribute__((ext_vector_type(2)));

__device__ __forceinline__ unsigned int pkh(float x, float y)
{
    const unsigned lo = __half_as_ushort(__float2half_rn(x));
    const unsigned hi = __half_as_ushort(__float2half_rn(y));
    return lo | (hi << 16);
}

__device__ __forceinline__ float dot2(unsigned int a, unsigned int b, float c)
{
#if __has_builtin(__builtin_amdgcn_fdot2)
    return __builtin_amdgcn_fdot2(__builtin_bit_cast(h2_t, a),
                                  __builtin_bit_cast(h2_t, b), c, false);
#else
    const h2_t ha = __builtin_bit_cast(h2_t, a);
    const h2_t hb = __builtin_bit_cast(h2_t, b);
    return c + (float)ha.x * (float)hb.x + (float)ha.y * (float)hb.y;
#endif
}

// sum of all 16 lanes within each 16-lane row, via DPP row_ror adds (no DS)
__device__ __forceinline__ float row16_sum(float x)
{
    int t;
    t = __builtin_amdgcn_update_dpp(0, __float_as_int(x), 0x121, 0xF, 0xF, true);
    x += __int_as_float(t);    // + ror1
    t = __builtin_amdgcn_update_dpp(0, __float_as_int(x), 0x122, 0xF, 0xF, true);
    x += __int_as_float(t);    // + ror2
    t = __builtin_amdgcn_update_dpp(0, __float_as_int(x), 0x124, 0xF, 0xF, true);
    x += __int_as_float(t);    // + ror4
    t = __builtin_amdgcn_update_dpp(0, __float_as_int(x), 0x128, 0xF, 0xF, true);
    x += __int_as_float(t);    // + ror8
    return x;
}

// add xor-16 partner within each 32-lane half (one ds_swizzle)
__device__ __forceinline__ float xor16_add(float x)
{
    const int y = __builtin_amdgcn_ds_swizzle(__float_as_int(x), 0x401F);
    return x + __int_as_float(y);
}

#define CONVB 128          // blocks doing h conversion
#define HISTB 384          // blocks doing histogram
__global__ __launch_bounds__(256) void pre_kernel(
    const float* __restrict__ h, unsigned int* __restrict__ hb,
    const int* __restrict__ target, const int* __restrict__ noise,
    unsigned int* __restrict__ counts, int N, int nhu)
{
    if (blockIdx.x < CONVB) {
        // linear packed-fp16 conversion: hb[i] = fp16(h[2i]) | fp16(h[2i+1])<<16
        int i = blockIdx.x * 256 + threadIdx.x;
        const int stride = CONVB * 256;
        for (; i < nhu; i += stride) {
            const float2 pr = reinterpret_cast<const float2*>(h)[i];
            hb[i] = pkh(pr.x, pr.y);
        }
    } else {
        int i = (blockIdx.x - CONVB) * 256 + threadIdx.x;
        const int stride = HISTB * 256;
        const int nn4 = (N * NSAMP) / 4;
        const int4* noise4 = reinterpret_cast<const int4*>(noise);
        for (int kk = i; kk < nn4; kk += stride) {
            const int4 vv = noise4[kk];
            atomicAdd(&counts[vv.x], 1u);
            atomicAdd(&counts[vv.y], 1u);
            atomicAdd(&counts[vv.z], 1u);
            atomicAdd(&counts[vv.w], 1u);
        }
        for (int kk = i; kk < N; kk += stride) atomicAdd(&counts[target[kk]], 1u);
    }
}

// single block, 1024 threads, 52 bins/thread, uint4 I/O (counts padded+zeroed)
__global__ __launch_bounds__(1024) void scan_kernel(
    const unsigned int* __restrict__ counts, unsigned int* __restrict__ cursor)
{
    const int tid = threadIdx.x;
    const uint4* c4 = reinterpret_cast<const uint4*>(counts) + tid * 13;
    uint4*      o4 = reinterpret_cast<uint4*>(cursor) + tid * 13;

    __shared__ unsigned int lds[1024];
    unsigned int s = 0;
    #pragma unroll
    for (int i = 0; i < 13; ++i) {
        const uint4 c = c4[i];
        s += c.x + c.y + c.z + c.w;
    }
    lds[tid] = s;
    __syncthreads();
    #pragma unroll
    for (int off = 1; off < 1024; off <<= 1) {
        unsigned int t = (tid >= off) ? lds[tid - off] : 0u;
        __syncthreads();
        lds[tid] += t;
        __syncthreads();
    }
    unsigned int run = (tid > 0) ? lds[tid - 1] : 0u;   // exclusive prefix
    #pragma unroll
    for (int i = 0; i < 13; ++i) {
        const uint4 c = c4[i];
        uint4 o;
        o.x = run;
        o.y = o.x + c.x;
        o.z = o.y + c.y;
        o.w = o.z + c.z;
        run = o.w + c.w;
        o4[i] = o;
    }
}

__global__ __launch_bounds__(256) void scatter_kernel(
    const int* __restrict__ target, const int* __restrict__ noise,
    unsigned int* __restrict__ cursor,
    unsigned int* __restrict__ sorted_pay, int N)
{
    int i = blockIdx.x * 256 + threadIdx.x;
    int stride = gridDim.x * 256;
    const int nn4 = (N * NSAMP) / 4;
    const int4* noise4 = reinterpret_cast<const int4*>(noise);
    for (int k = i; k < nn4; k += stride) {
        const int4 vv = noise4[k];
        const int kk = k * 4;
        #pragma unroll
        for (int j = 0; j < 4; ++j) {
            const int v    = (j == 0) ? vv.x : (j == 1) ? vv.y : (j == 2) ? vv.z : vv.w;
            const int idx  = kk + j;
            const int tok  = idx >> 9;            // /512
            const int slot = (idx & 511) + 1;     // noise -> slots 1..512
            const unsigned int pos = atomicAdd(&cursor[v], 1u);
            sorted_pay[pos] = ((unsigned int)tok << 10) | (unsigned int)slot;
        }
    }
    for (int k = i; k < N; k += stride) {
        const int v = target[k];
        const unsigned int pos = atomicAdd(&cursor[v], 1u);
        sorted_pay[pos] = ((unsigned int)k << 10);   // slot 0
    }
}

// one wave per vocab run; 2 occ/iter; 3-stage pipeline; fp16 dot2; DPP reduce
#define GTPB 256
__global__ __launch_bounds__(GTPB) void gather_run_kernel(
    const unsigned int* __restrict__ hb,          // packed fp16 h, 384 u32/row
    const float* __restrict__ W,
    const unsigned int* __restrict__ counts,
    const unsigned int* __restrict__ cursor,      // end offsets after scatter
    const unsigned int* __restrict__ sorted_pay,
    float* __restrict__ logits)
{
    const int v = blockIdx.x * (GTPB / 64) + (threadIdx.x >> 6);
    if (v >= VOCAB) return;
    const int cnt = (int)counts[v];
    if (cnt == 0) return;
    const int start = (int)cursor[v] - cnt;
    const int lane  = threadIdx.x & 63;
    const int last  = cnt - 1;

    // W row lane-slice -> packed fp16, registers for the whole run.
    // Lane covers elems [8*lane, 8*lane+8) and [512+4*lane, 512+4*lane+4).
    const float4* wr = reinterpret_cast<const float4*>(W + (size_t)v * HDIM);
    const float4 a0 = wr[2 * lane], a1 = wr[2 * lane + 1], a2 = wr[128 + lane];
    const unsigned wp0 = pkh(a0.x, a0.y), wp1 = pkh(a0.z, a0.w),
                   wp2 = pkh(a1.x, a1.y), wp3 = pkh(a1.z, a1.w),
                   wp4 = pkh(a2.x, a2.y), wp5 = pkh(a2.z, a2.w);

    const unsigned int* sp = sorted_pay + start;
    #define CLMP(k) ((k) < last ? (k) : last)

    // prologue: stages 0 (pays 0,1) and 1 (pays 2,3)
    unsigned pay0 = sp[0];
    unsigned pay1 = sp[CLMP(1)];
    unsigned pay2 = sp[CLMP(2)];
    unsigned pay3 = sp[CLMP(3)];
    const unsigned* r0 = hb + (size_t)(pay0 >> 10) * 384;
    const unsigned* r1 = hb + (size_t)(pay1 >> 10) * 384;
    const unsigned* r2 = hb + (size_t)(pay2 >> 10) * 384;
    const unsigned* r3 = hb + (size_t)(pay3 >> 10) * 384;
    uint4 x0 = reinterpret_cast<const uint4*>(r0)[lane];
    uint2 y0 = reinterpret_cast<const uint2*>(r0 + 256)[lane];
    uint4 x1 = reinterpret_cast<const uint4*>(r1)[lane];
    uint2 y1 = reinterpret_cast<const uint2*>(r1 + 256)[lane];
    uint4 x2 = reinterpret_cast<const uint4*>(r2)[lane];
    uint2 y2 = reinterpret_cast<const uint2*>(r2 + 256)[lane];
    uint4 x3 = reinterpret_cast<const uint4*>(r3)[lane];
    uint2 y3 = reinterpret_cast<const uint2*>(r3 + 256)[lane];

    const bool hi = lane >= 32;

    for (int j = 0; j < cnt; j += 2) {
        // prefetch stage j+4, j+5 (clamped)
        const unsigned payn0 = sp[CLMP(j + 4)];
        const unsigned payn1 = sp[CLMP(j + 5)];
        const unsigned* rn0 = hb + (size_t)(payn0 >> 10) * 384;
        const unsigned* rn1 = hb + (size_t)(payn1 >> 10) * 384;
        const uint4 nx0 = reinterpret_cast<const uint4*>(rn0)[lane];
        const uint2 ny0 = reinterpret_cast<const uint2*>(rn0 + 256)[lane];
        const uint4 nx1 = reinterpret_cast<const uint4*>(rn1)[lane];
        const uint2 ny1 = reinterpret_cast<const uint2*>(rn1 + 256)[lane];

        // two occurrences, 6 dot2 each, 2 chains per occurrence for ILP
        float s0a = dot2(x0.x, wp0, 0.f), s1a = dot2(x1.x, wp0, 0.f);
        float s0b = dot2(x0.y, wp1, 0.f), s1b = dot2(x1.y, wp1, 0.f);
        s0a = dot2(x0.z, wp2, s0a);  s1a = dot2(x1.z, wp2, s1a);
        s0b = dot2(x0.w, wp3, s0b);  s1b = dot2(x1.w, wp3, s1b);
        s0a = dot2(y0.x, wp4, s0a);  s1a = dot2(y1.x, wp4, s1a);
        s0b = dot2(y0.y, wp5, s0b);  s1b = dot2(y1.y, wp5, s1b);
        float s0 = s0a + s0b, s1 = s1a + s1b;

        // reduce: intra-16 via DPP (VALU), xor16 via 1 ds_swizzle each,
        // then ONE shared shfl_xor(32) finishes both occurrences.
        s0 = xor16_add(row16_sum(s0));   // 32-half sums of occ0
        s1 = xor16_add(row16_sum(s1));   // 32-half sums of occ1
        float c = hi ? s1 : s0;          // lo: S0_lo | hi: S1_hi
        float d = hi ? s0 : s1;          // lo: S1_lo | hi: S0_hi
        c += __shfl_xor(d, 32, 64);      // lo: S0 full | hi: S1 full

        if (lane == 0)
            logits[(size_t)(pay0 >> 10) * NLOG + (pay0 & 1023u)] = c;
        else if (lane == 32 && j + 1 < cnt)
            logits[(size_t)(pay1 >> 10) * NLOG + (pay1 & 1023u)] = c;

        // rotate pipeline
        pay0 = pay2; pay1 = pay3; pay2 = payn0; pay3 = payn1;
        x0 = x2; y0 = y2; x1 = x3; y1 = y3;
        x2 = nx0; y2 = ny0; x3 = nx1; y3 = ny1;
    }
    #undef CLMP
}

__global__ __launch_bounds__(256) void softmax_loss_kernel(
    const float* __restrict__ logits, float* __restrict__ loss_per_token)
{
    const int n    = blockIdx.x;
    const int tid  = threadIdx.x;
    const int lane = tid & 63;
    const int wave = tid >> 6;
    const float* row = logits + (size_t)n * NLOG;

    __shared__ float red[4];
    __shared__ float red2[4][2];

    float lmax = -INFINITY;
    for (int r = tid; r < NLOG; r += 256) lmax = fmaxf(lmax, row[r]);
    #pragma unroll
    for (int off = 32; off; off >>= 1) lmax = fmaxf(lmax, __shfl_xor(lmax, off, 64));
    if (lane == 0) red[wave] = lmax;
    __syncthreads();
    lmax = fmaxf(fmaxf(red[0], red[1]), fmaxf(red[2], red[3]));

    float esum = 0.f, lsum = 0.f;
    for (int r = tid; r < NLOG; r += 256) {
        const float l = row[r];
        esum += __expf(l - lmax);
        if (r > 0) lsum += l;
    }
    #pragma unroll
    for (int off = 32; off; off >>= 1) {
        esum += __shfl_xor(esum, off, 64);
        lsum += __shfl_xor(lsum, off, 64);
    }
    if (lane == 0) { red2[wave][0] = esum; red2[wave][1] = lsum; }
    __syncthreads();

    if (tid == 0) {
        esum = red2[0][0] + red2[1][0] + red2[2][0] + red2[3][0];
        lsum = red2[0][1] + red2[1][1] + red2[2][1] + red2[3][1];
        const float lse  = lmax + logf(esum);
        const float l0   = row[0];
        const float loss = -0.9f * (l0 - lse)
                         - (0.1f / 512.f) * (lsum - 512.f * lse);
        loss_per_token[n] = loss;
    }
}

__global__ __launch_bounds__(256) void reduce_mean_kernel(
    const float* __restrict__ x, float* __restrict__ out, int n)
{
    const int tid = threadIdx.x;
    float s = 0.f;
    for (int i = tid; i < n; i += 256) s += x[i];
    #pragma unroll
    for (int off = 32; off; off >>= 1) s += __shfl_xor(s, off, 64);
    __shared__ float red[4];
    if ((tid & 63) == 0) red[tid >> 6] = s;
    __syncthreads();
    if (tid == 0) out[0] = (red[0] + red[1] + red[2] + red[3]) / (float)n;
}

// ------------------------- legacy fallback (R1) ----------------------------
__global__ __launch_bounds__(512) void nce_token_kernel(
    const float* __restrict__ h, const float* __restrict__ W,
    const int* __restrict__ target, const int* __restrict__ noise,
    float* __restrict__ loss_per_token)
{
    const int n    = blockIdx.x;
    const int tid  = threadIdx.x;
    const int lane = tid & 63;
    const int wave = tid >> 6;

    __shared__ float  logits[NLOG];
    __shared__ float4 hsm[HDIM / 4];
    __shared__ float  red[8];
    __shared__ float  red2[8][2];

    const float4* hrow = reinterpret_cast<const float4*>(h + (size_t)n * HDIM);
    if (tid < HDIM / 4) hsm[tid] = hrow[tid];
    __syncthreads();

    const float4 h0 = hsm[lane];
    const float4 h1 = hsm[lane + 64];
    const float4 h2 = hsm[lane + 128];
    const int* nrow = noise + (size_t)n * NSAMP;

    for (int r = wave; r < NLOG; r += 8) {
        const int row = (r == 0) ? target[n] : nrow[r - 1];
        const float4* wr = reinterpret_cast<const float4*>(W + (size_t)row * HDIM);
        const float4 w0 = wr[lane];
        const float4 w1 = wr[lane + 64];
        const float4 w2 = wr[lane + 128];
        float s;
        s  = h0.x * w0.x + h0.y * w0.y + h0.z * w0.z + h0.w * w0.w;
        s += h1.x * w1.x + h1.y * w1.y + h1.z * w1.z + h1.w * w1.w;
        s += h2.x * w2.x + h2.y * w2.y + h2.z * w2.z + h2.w * w2.w;
        #pragma unroll
        for (int off = 32; off; off >>= 1) s += __shfl_xor(s, off, 64);
        if (lane == 0) logits[r] = s;
    }
    __syncthreads();

    float lmax = -INFINITY;
    for (int r = tid; r < NLOG; r += 512) lmax = fmaxf(lmax, logits[r]);
    #pragma unroll
    for (int off = 32; off; off >>= 1) lmax = fmaxf(lmax, __shfl_xor(lmax, off, 64));
    if (lane == 0) red[wave] = lmax;
    __syncthreads();
    if (wave == 0) {
        float m = (lane < 8) ? red[lane] : -INFINITY;
        #pragma unroll
        for (int off = 4; off; off >>= 1) m = fmaxf(m, __shfl_xor(m, off, 64));
        if (lane == 0) red[0] = m;
    }
    __syncthreads();
    lmax = red[0];

    float esum = 0.f, lsum = 0.f;
    for (int r = tid; r < NLOG; r += 512) {
        const float l = logits[r];
        esum += __expf(l - lmax);
        if (r > 0) lsum += l;
    }
    #pragma unroll
    for (int off = 32; off; off >>= 1) {
        esum += __shfl_xor(esum, off, 64);
        lsum += __shfl_xor(lsum, off, 64);
    }
    if (lane == 0) { red2[wave][0] = esum; red2[wave][1] = lsum; }
    __syncthreads();

    if (tid == 0) {
        esum = 0.f; lsum = 0.f;
        #pragma unroll
        for (int w = 0; w < 8; ++w) { esum += red2[w][0]; lsum += red2[w][1]; }
        const float lse  = lmax + logf(esum);
        const float loss = -0.9f * (logits[0] - lse)
                         - (0.1f / 512.f) * (lsum - 512.f * lse);
        loss_per_token[n] = loss;
    }
}
// ---------------------------------------------------------------------------

extern "C" void kernel_launch(void* const* d_in, const int* in_sizes, int n_in,
                              void* d_out, int out_size, void* d_ws, size_t ws_size,
                              hipStream_t stream)
{
    const float* h      = (const float*)d_in[0];   // [N, 768] fp32
    const float* W      = (const float*)d_in[1];   // [50257, 768] fp32
    const int*   target = (const int*)d_in[2];     // [N] int32
    const int*   noise  = (const int*)d_in[3];     // [N, 512] int32
    float*       out    = (float*)d_out;
    const int    N      = in_sizes[2];             // 1024 tokens
    const int    nocc   = N * NLOG;                // 525312
    const int    nh2    = N * HDIM / 2;            // 393216 packed u32

    // ws layout (u32/f32 elements): counts[PADV] cursor[PADV] pay[nocc]
    //                               hb[nh2] logits[nocc] loss[N]
    unsigned int* counts     = (unsigned int*)d_ws;
    unsigned int* cursor     = counts + PADV;
    unsigned int* sorted_pay = cursor + PADV;
    unsigned int* hb         = sorted_pay + nocc;
    float*        logits     = (float*)(hb + nh2);
    float*        loss       = logits + nocc;
    const size_t  need_bytes = (size_t)(2 * PADV + 2 * nocc + nh2 + N) * 4;

    if (ws_size < need_bytes) {
        // fallback: direct gather path (R1)
        float* ws = (float*)d_ws;
        nce_token_kernel<<<N, 512, 0, stream>>>(h, W, target, noise, ws);
        reduce_mean_kernel<<<1, 256, 0, stream>>>(ws, out, N);
        return;
    }

    hipMemsetAsync(counts, 0, (size_t)PADV * 4, stream);
    pre_kernel<<<CONVB + HISTB, 256, 0, stream>>>(h, hb, target, noise,
                                                  counts, N, nh2);
    scan_kernel<<<1, 1024, 0, stream>>>(counts, cursor);
    scatter_kernel<<<512, 256, 0, stream>>>(target, noise, cursor, sorted_pay, N);
    const int gblocks = (VOCAB + (GTPB / 64) - 1) / (GTPB / 64);
    gather_run_kernel<<<gblocks, GTPB, 0, stream>>>(hb, W, counts, cursor,
                                                    sorted_pay, logits);
    softmax_loss_kernel<<<N, 256, 0, stream>>>(logits, loss);
    reduce_mean_kernel<<<1, 256, 0, stream>>>(loss, out, N);
}